// Round 16
// baseline (342.274 us; speedup 1.0000x reference)
//
#include <hip/hip_runtime.h>
#include <hip/hip_bf16.h>
#include <math.h>

#define HH 128
#define FF 128
#define GG 50
#define NLAYERS 6
#define NPB 16
#define TAB 8192
#define TABH 9.765625e-4f    // 8.0 / 8192
#define TABINVH 1024.0f
#define SCB 32               // scan blocks
#define DP 16                // edge pipeline depth

typedef __attribute__((ext_vector_type(8))) short bf16x8;
typedef __attribute__((ext_vector_type(4))) float f32x4;

static __device__ __forceinline__ float ssp(float x) {
    return fmaxf(x, 0.f) + __logf(1.f + __expf(-fabsf(x))) - 0.6931471805599453f;
}

static __device__ __forceinline__ short f2bf(float x) {
    union { float f; unsigned u; } c; c.f = x;
    unsigned r = (c.u + 0x7FFF + ((c.u >> 16) & 1)) >> 16;
    return (short)r;
}

static __device__ __forceinline__ float bf2f_lo(unsigned p) {
    union { unsigned u; float f; } c; c.u = p << 16; return c.f;
}
static __device__ __forceinline__ float bf2f_hi(unsigned p) {
    union { unsigned u; float f; } c; c.u = p & 0xFFFF0000u; return c.f;
}

// ---------------- sort pipeline ----------------
__global__ void hist_kernel(const int* __restrict__ col, int* __restrict__ counts, int E_) {
    int e = blockIdx.x * 256 + threadIdx.x;
    if (e < E_) atomicAdd(&counts[col[e]], 1);
}

__global__ __launch_bounds__(1024) void pscan1_kernel(const int* __restrict__ counts,
                                                      int* __restrict__ psum, int N_) {
    __shared__ int wsum[16];
    const int tid = threadIdx.x;
    const int lane = tid & 63, wid = tid >> 6;
    const int chunk = (N_ + SCB - 1) / SCB;
    int i = blockIdx.x * chunk + tid;
    int val = (tid < chunk && i < N_) ? counts[i] : 0;
#pragma unroll
    for (int d = 1; d < 64; d <<= 1) val += __shfl_xor(val, d, 64);
    if (lane == 0) wsum[wid] = val;
    __syncthreads();
    if (wid == 0) {
        int s = (lane < 16) ? wsum[lane] : 0;
#pragma unroll
        for (int d = 1; d < 16; d <<= 1) s += __shfl_xor(s, d, 64);
        if (lane == 0) psum[blockIdx.x] = s;
    }
}

__global__ void pscan2_kernel(const int* __restrict__ psum, int* __restrict__ pbase) {
    const int tid = threadIdx.x;  // 64 threads
    int v = (tid < SCB) ? psum[tid] : 0;
    int x = v;
#pragma unroll
    for (int d = 1; d < 64; d <<= 1) {
        int t = __shfl_up(x, d, 64);
        if (tid >= d) x += t;
    }
    if (tid < SCB) pbase[tid] = x - v;  // exclusive
}

__global__ __launch_bounds__(1024) void pscan3_kernel(const int* __restrict__ counts,
                                                      const int* __restrict__ pbase,
                                                      int* __restrict__ offsets,
                                                      int* __restrict__ woff, int N_) {
    __shared__ int wsum[16];
    const int tid = threadIdx.x;
    const int lane = tid & 63, wid = tid >> 6;
    const int chunk = (N_ + SCB - 1) / SCB;
    int i = blockIdx.x * chunk + tid;
    int val = (tid < chunk && i < N_) ? counts[i] : 0;
    int x = val;
#pragma unroll
    for (int d = 1; d < 64; d <<= 1) {
        int t = __shfl_up(x, d, 64);
        if (lane >= d) x += t;
    }
    if (lane == 63) wsum[wid] = x;
    __syncthreads();
    if (wid == 0) {
        int s = (lane < 16) ? wsum[lane] : 0;
#pragma unroll
        for (int d = 1; d < 16; d <<= 1) {
            int t = __shfl_up(s, d, 64);
            if (lane >= d) s += t;
        }
        if (lane < 16) wsum[lane] = s;
    }
    __syncthreads();
    int woffset = (wid > 0) ? wsum[wid - 1] : 0;
    if (tid < chunk && i < N_) {
        int ex = pbase[blockIdx.x] + woffset + x - val;
        offsets[i] = ex;
        woff[i] = ex;
    }
}

// scatter: CSR slots + packed per-edge meta row(17b) | ix(13b)<<17 (nearest table idx)
__global__ void scatter_kernel(const float* __restrict__ pos,
                               const float* __restrict__ offs,
                               const int* __restrict__ row,
                               const int* __restrict__ col,
                               int* __restrict__ woff,
                               int* __restrict__ meta, int E_) {
    int e = blockIdx.x * 256 + threadIdx.x;
    if (e >= E_) return;
    int r = row[e], c = col[e];
    float dx = pos[c * 3 + 0] + offs[e * 3 + 0] - pos[r * 3 + 0];
    float dy = pos[c * 3 + 1] + offs[e * 3 + 1] - pos[r * 3 + 1];
    float dz = pos[c * 3 + 2] + offs[e * 3 + 2] - pos[r * 3 + 2];
    float d = sqrtf(dx * dx + dy * dy + dz * dz);
    int ix = (int)(d * TABINVH + 0.5f);   // nearest
    if (ix > TAB - 1) ix = TAB - 1;
    int p = atomicAdd(&woff[c], 1);
    meta[p] = r | (ix << 17);             // requires N < 131072
}

// ------------- prep: transpose + bf16 all weights -------------
__global__ __launch_bounds__(256) void prep_kernel(
    const float* __restrict__ w1, const float* __restrict__ w2,
    const float* __restrict__ u1, const float* __restrict__ u2,
    const float* __restrict__ lin_w,
    short* __restrict__ w1t, short* __restrict__ w2t,
    short* __restrict__ u1t, short* __restrict__ u2t, short* __restrict__ lin_wt) {
    int idx = blockIdx.x * 256 + threadIdx.x;
    if (idx < NLAYERS * FF * FF) {
        int l = idx >> 14, r = idx & 16383, a = r >> 7, b = r & 127;
        size_t src = (size_t)l * FF * FF + (size_t)b * FF + a;
        w2t[idx] = f2bf(w2[src]);
        u1t[idx] = f2bf(u1[src]);
        u2t[idx] = f2bf(u2[src]);
        lin_wt[idx] = f2bf(lin_w[src]);
    }
    if (idx < NLAYERS * FF * 64) {
        int l = idx >> 13, r = idx & 8191, fo = r >> 6, g = r & 63;
        w1t[idx] = f2bf(g < GG ? w1[((size_t)l * GG + g) * FF + fo] : 0.f);
    }
}

// ------- vproj0 = v(f32) @ lin_w[0] via MFMA, bf16 out; also copies v -> vbuf -------
__global__ __launch_bounds__(256) void vproj0_kernel(const float* __restrict__ vb,
                                                     const short* __restrict__ lwt,
                                                     unsigned short* __restrict__ out,
                                                     float* __restrict__ vbuf_out,
                                                     int N_) {
    const int tid = threadIdx.x;
    const int lane = tid & 63, wave = tid >> 6;
    const int l15 = lane & 15, l4 = lane >> 4;
    const int n0 = wave * 32;
    const int nb0 = blockIdx.x * 64;
    // fused residual-state init: vbuf = v
    for (int i = tid; i < 64 * 32; i += 256) {
        int r = i >> 5, c = i & 31;
        int gn = nb0 + r;
        if (gn < N_)
            *(float4*)&vbuf_out[(size_t)gn * HH + c * 4] =
                *(const float4*)&vb[(size_t)gn * HH + c * 4];
    }
    bf16x8 bw[2][4];
#pragma unroll
    for (int n = 0; n < 2; n++)
#pragma unroll
        for (int ks = 0; ks < 4; ks++)
            bw[n][ks] = *(const bf16x8*)&lwt[(n0 + n * 16 + l15) * 128 + ks * 32 + l4 * 8];
#pragma unroll
    for (int m = 0; m < 4; m++) {
        f32x4 acc0 = {0.f, 0.f, 0.f, 0.f}, acc1 = {0.f, 0.f, 0.f, 0.f};
        int arow = nb0 + m * 16 + l15;
        const float* ap = &vb[(size_t)(arow < N_ ? arow : 0) * HH];
#pragma unroll
        for (int ks = 0; ks < 4; ks++) {
            float4 x0 = *(const float4*)&ap[ks * 32 + l4 * 8];
            float4 x1 = *(const float4*)&ap[ks * 32 + l4 * 8 + 4];
            bf16x8 a = {f2bf(x0.x), f2bf(x0.y), f2bf(x0.z), f2bf(x0.w),
                        f2bf(x1.x), f2bf(x1.y), f2bf(x1.z), f2bf(x1.w)};
            acc0 = __builtin_amdgcn_mfma_f32_16x16x32_bf16(a, bw[0][ks], acc0, 0, 0, 0);
            acc1 = __builtin_amdgcn_mfma_f32_16x16x32_bf16(a, bw[1][ks], acc1, 0, 0, 0);
        }
#pragma unroll
        for (int r = 0; r < 4; r++) {
            int gn = nb0 + m * 16 + l4 * 4 + r;
            if (gn < N_) {
                out[(size_t)gn * FF + n0 + l15] = (unsigned short)f2bf(acc0[r]);
                out[(size_t)gn * FF + n0 + 16 + l15] = (unsigned short)f2bf(acc1[r]);
            }
        }
    }
}

// -------- table build: tab[l][i][f], i = nearest grid point ----
__global__ __launch_bounds__(256) void tab_kernel(
    const short* __restrict__ w1t, const float* __restrict__ b1,
    const short* __restrict__ w2t, const float* __restrict__ b2,
    unsigned short* __restrict__ tab) {
    __shared__ __align__(16) short h1_s[64 * 136];
    const int tid = threadIdx.x;
    const int lane = tid & 63, wave = tid >> 6;
    const int l15 = lane & 15, l4 = lane >> 4;
    const int n0w = wave * 32;
    const int l = blockIdx.x / (TAB / 64);
    const int tb0 = (blockIdx.x % (TAB / 64)) * 64;
    const short* w1l = w1t + (size_t)l * FF * 64;
    const short* w2l = w2t + (size_t)l * FF * FF;
    unsigned short* tabl = tab + (size_t)l * TAB * FF;

    bf16x8 bw1[2][2], bw2[2][4];
    float bias1[2], bias2[2];
#pragma unroll
    for (int n = 0; n < 2; n++) {
        const int fo = n0w + n * 16 + l15;
        bias1[n] = b1[(size_t)l * FF + fo];
        bias2[n] = b2[(size_t)l * FF + fo];
#pragma unroll
        for (int ks = 0; ks < 2; ks++)
            bw1[n][ks] = *(const bf16x8*)&w1l[fo * 64 + ks * 32 + l4 * 8];
#pragma unroll
        for (int ks = 0; ks < 4; ks++)
            bw2[n][ks] = *(const bf16x8*)&w2l[fo * 128 + ks * 32 + l4 * 8];
    }

    const float STEP = 5.0f / 49.0f;
    const float COEFF = -0.5f / (STEP * STEP);
#pragma unroll
    for (int m = 0; m < 4; m++) {
        float d = (float)(tb0 + m * 16 + l15) * TABH;
        bf16x8 a0, a1;
#pragma unroll
        for (int j = 0; j < 8; j++) {
            int g0 = l4 * 8 + j;
            float x0 = fmaf((float)g0, -STEP, d);
            a0[j] = f2bf(__expf(COEFF * x0 * x0));
            int g1 = 32 + l4 * 8 + j;
            float x1 = fmaf((float)g1, -STEP, d);
            a1[j] = (g1 < GG) ? f2bf(__expf(COEFF * x1 * x1)) : (short)0;
        }
#pragma unroll
        for (int n = 0; n < 2; n++) {
            f32x4 acc = {bias1[n], bias1[n], bias1[n], bias1[n]};
            acc = __builtin_amdgcn_mfma_f32_16x16x32_bf16(a0, bw1[n][0], acc, 0, 0, 0);
            acc = __builtin_amdgcn_mfma_f32_16x16x32_bf16(a1, bw1[n][1], acc, 0, 0, 0);
            const int f = n0w + n * 16 + l15;
#pragma unroll
            for (int r = 0; r < 4; r++)
                h1_s[(m * 16 + l4 * 4 + r) * 136 + f] = f2bf(ssp(acc[r]));
        }
    }
    __syncthreads();

#pragma unroll
    for (int m = 0; m < 4; m++) {
        f32x4 accA = {bias2[0], bias2[0], bias2[0], bias2[0]};
        f32x4 accB = {bias2[1], bias2[1], bias2[1], bias2[1]};
#pragma unroll
        for (int ks = 0; ks < 4; ks++) {
            bf16x8 a = *(const bf16x8*)&h1_s[(m * 16 + l15) * 136 + ks * 32 + l4 * 8];
            accA = __builtin_amdgcn_mfma_f32_16x16x32_bf16(a, bw2[0][ks], accA, 0, 0, 0);
            accB = __builtin_amdgcn_mfma_f32_16x16x32_bf16(a, bw2[1][ks], accB, 0, 0, 0);
        }
#pragma unroll
        for (int r = 0; r < 4; r++) {
            int entry = tb0 + m * 16 + l4 * 4 + r;
            float de = (float)entry * TABH;
            float C = 0.5f * (cosf(de * 0.6283185307179586f) + 1.0f);
            tabl[(size_t)entry * FF + n0w + l15] = (unsigned short)f2bf(accA[r] * C);
            tabl[(size_t)entry * FF + n0w + 16 + l15] = (unsigned short)f2bf(accB[r] * C);
        }
    }
}

// ===== fused layer: 8-wave/512-thr, NPB=16; wave walks its 2 nodes' contiguous
// CSR range in ONE DP=16 pipeline (scalar boundary selects accumulator) =====
__global__ __launch_bounds__(512) void layer_kernel(
    const int* __restrict__ meta,
    const int* __restrict__ off_start, const int* __restrict__ off_end,
    const unsigned* __restrict__ tab, const unsigned* __restrict__ vin,
    const short* __restrict__ u1t, const float* __restrict__ ub1,
    const short* __restrict__ u2t, const float* __restrict__ ub2,
    float* __restrict__ vb, const short* __restrict__ lwt_next,
    unsigned short* __restrict__ vout, int N_) {
    __shared__ __align__(16) float agg_s[NPB * 132];
    __shared__ __align__(16) short t1_s[NPB * 136];
    short* t2_s = (short*)agg_s;

    const int tid = threadIdx.x;
    const int lane = tid & 63, wave = tid >> 6;   // 8 waves
    const int l15 = lane & 15, l4 = lane >> 4;
    const int n0c = wave * 16;
    const int nb0 = blockIdx.x * NPB;

    // ---- edge aggregation: wave owns nodes {2w, 2w+1}; single contiguous walk
    {
        const int nA = nb0 + wave * 2;
        const int nB = nA + 1;
        float a0A = 0.f, a1A = 0.f, a0B = 0.f, a1B = 0.f;
        if (nA < N_) {
            const int e0 = __builtin_amdgcn_readfirstlane(off_start[nA]);
            const int bnd = __builtin_amdgcn_readfirstlane(off_end[nA]);
            const int e1 = (nB < N_) ? __builtin_amdgcn_readfirstlane(off_end[nB]) : bnd;
            if (e1 > e0) {
                int mmn[DP];
#pragma unroll
                for (int j = 0; j < DP; j++) {
                    int e = e0 + j; if (e >= e1) e = e1 - 1;
                    mmn[j] = meta[e];
                }
                for (int base = e0; base < e1; base += DP) {
                    int mw[DP];
#pragma unroll
                    for (int j = 0; j < DP; j++)
                        mw[j] = __builtin_amdgcn_readfirstlane(mmn[j]);
                    unsigned tp[DP], vp[DP];
#pragma unroll
                    for (int j = 0; j < DP; j++) {
                        const int r_ = mw[j] & 0x1ffff;
                        const int ix = (int)((unsigned)mw[j] >> 17);
                        tp[j] = tab[(size_t)ix * 64 + lane];
                        vp[j] = vin[(size_t)r_ * 64 + lane];
                    }
                    const int nb2 = base + DP;
                    if (nb2 < e1) {
#pragma unroll
                        for (int j = 0; j < DP; j++) {
                            int e = nb2 + j; if (e >= e1) e = e1 - 1;
                            mmn[j] = meta[e];
                        }
                    }
#pragma unroll
                    for (int j = 0; j < DP; j++) {
                        const int e = base + j;
                        if (e < e1) {            // scalar-uniform
                            const float w0 = bf2f_lo(tp[j]);
                            const float w1 = bf2f_hi(tp[j]);
                            if (e < bnd) {       // scalar-uniform node select
                                a0A = fmaf(w0, bf2f_lo(vp[j]), a0A);
                                a1A = fmaf(w1, bf2f_hi(vp[j]), a1A);
                            } else {
                                a0B = fmaf(w0, bf2f_lo(vp[j]), a0B);
                                a1B = fmaf(w1, bf2f_hi(vp[j]), a1B);
                            }
                        }
                    }
                }
            }
        }
        const int nl = wave * 2;
        agg_s[nl * 132 + 2 * lane] = a0A;
        agg_s[nl * 132 + 2 * lane + 1] = a1A;
        agg_s[(nl + 1) * 132 + 2 * lane] = a0B;
        agg_s[(nl + 1) * 132 + 2 * lane + 1] = a1B;
    }
    __syncthreads();

    // ---- MLP GEMM1: t1 = ssp(agg @ u1 + ub1); wave does 16x16 tile
    {
        bf16x8 bw[4];
        const float bias = ub1[n0c + l15];
#pragma unroll
        for (int ks = 0; ks < 4; ks++)
            bw[ks] = *(const bf16x8*)&u1t[(n0c + l15) * 128 + ks * 32 + l4 * 8];
        const float* ap = &agg_s[l15 * 132];
        f32x4 acc = {bias, bias, bias, bias};
#pragma unroll
        for (int ks = 0; ks < 4; ks++) {
            float4 x0 = *(const float4*)&ap[ks * 32 + l4 * 8];
            float4 x1 = *(const float4*)&ap[ks * 32 + l4 * 8 + 4];
            bf16x8 a = {f2bf(x0.x), f2bf(x0.y), f2bf(x0.z), f2bf(x0.w),
                        f2bf(x1.x), f2bf(x1.y), f2bf(x1.z), f2bf(x1.w)};
            acc = __builtin_amdgcn_mfma_f32_16x16x32_bf16(a, bw[ks], acc, 0, 0, 0);
        }
#pragma unroll
        for (int r = 0; r < 4; r++) {
            int er = l4 * 4 + r;
            t1_s[er * 136 + n0c + l15] = f2bf(ssp(acc[r]));
        }
    }
    __syncthreads();

    // ---- MLP GEMM2: v_new = v + (t1 @ u2 + ub2); write vb + t2_s (aliases agg)
    {
        bf16x8 bw[4];
        const float bias = ub2[n0c + l15];
#pragma unroll
        for (int ks = 0; ks < 4; ks++)
            bw[ks] = *(const bf16x8*)&u2t[(n0c + l15) * 128 + ks * 32 + l4 * 8];
        f32x4 acc = {bias, bias, bias, bias};
#pragma unroll
        for (int ks = 0; ks < 4; ks++) {
            bf16x8 a = *(const bf16x8*)&t1_s[(l15) * 136 + ks * 32 + l4 * 8];
            acc = __builtin_amdgcn_mfma_f32_16x16x32_bf16(a, bw[ks], acc, 0, 0, 0);
        }
        __syncthreads();   // agg reads done before t2 overwrite
#pragma unroll
        for (int r = 0; r < 4; r++) {
            int er = l4 * 4 + r;
            int gn = nb0 + er;
            if (gn < N_) {
                size_t i0 = (size_t)gn * HH + n0c + l15;
                float v0 = vb[i0] + acc[r];
                vb[i0] = v0;
                t2_s[er * 136 + n0c + l15] = f2bf(v0);
            } else {
                t2_s[er * 136 + n0c + l15] = 0;
            }
        }
    }
    __syncthreads();

    // ---- MLP GEMM3: vout = v_new @ lin_w[l+1] (bf16)
    if (lwt_next) {
        bf16x8 bw[4];
#pragma unroll
        for (int ks = 0; ks < 4; ks++)
            bw[ks] = *(const bf16x8*)&lwt_next[(n0c + l15) * 128 + ks * 32 + l4 * 8];
        f32x4 acc = {0.f, 0.f, 0.f, 0.f};
#pragma unroll
        for (int ks = 0; ks < 4; ks++) {
            bf16x8 a = *(const bf16x8*)&t2_s[(l15) * 136 + ks * 32 + l4 * 8];
            acc = __builtin_amdgcn_mfma_f32_16x16x32_bf16(a, bw[ks], acc, 0, 0, 0);
        }
#pragma unroll
        for (int r = 0; r < 4; r++) {
            int gn = nb0 + l4 * 4 + r;
            if (gn < N_) {
                vout[(size_t)gn * FF + n0c + l15] = (unsigned short)f2bf(acc[r]);
            }
        }
    }
}

extern "C" void kernel_launch(void* const* d_in, const int* in_sizes, int n_in,
                              void* d_out, int out_size, void* d_ws, size_t ws_size,
                              hipStream_t stream) {
    const float* v = (const float*)d_in[0];
    const float* pos = (const float*)d_in[1];
    const float* offs = (const float*)d_in[2];
    const int* edges = (const int*)d_in[3];
    const float* lin_w = (const float*)d_in[4];
    const float* w1 = (const float*)d_in[5];
    const float* b1 = (const float*)d_in[6];
    const float* w2 = (const float*)d_in[7];
    const float* b2 = (const float*)d_in[8];
    const float* u1 = (const float*)d_in[9];
    const float* ub1 = (const float*)d_in[10];
    const float* u2 = (const float*)d_in[11];
    const float* ub2 = (const float*)d_in[12];

    const int N = in_sizes[0] / HH;
    const int E = in_sizes[3] / 2;
    const int* row = edges;
    const int* col = edges + E;

    char* base = (char*)d_ws;
    int* counts = (int*)base;    base += (size_t)N * 4;
    int* woff = (int*)base;      base += (size_t)N * 4;
    int* offsets = (int*)base;   base += (size_t)N * 4;
    int* psum = (int*)base;      base += (size_t)SCB * 4;
    int* pbase = (int*)base;     base += (size_t)SCB * 4 + 24;  // keep align
    int* meta = (int*)base;      base += (size_t)E * 4;
    unsigned short* vprojA = (unsigned short*)base; base += (size_t)N * FF * 2;
    unsigned short* vprojB = (unsigned short*)base; base += (size_t)N * FF * 2;
    short* w1t = (short*)base;   base += (size_t)NLAYERS * FF * 64 * 2;
    short* w2t = (short*)base;   base += (size_t)NLAYERS * FF * FF * 2;
    short* u1t = (short*)base;   base += (size_t)NLAYERS * FF * FF * 2;
    short* u2t = (short*)base;   base += (size_t)NLAYERS * FF * FF * 2;
    short* lin_wt = (short*)base; base += (size_t)NLAYERS * FF * FF * 2;
    unsigned short* tab = (unsigned short*)base;  // 6 * 8192 * 128 bf16 = 12.6 MB

    float* vbuf = (float*)d_out;   // residual state lives in d_out

    const int EB = (E + 255) / 256;
    const int NB64 = (N + 63) / 64;
    const int NBn = (N + NPB - 1) / NPB;

    hipMemsetAsync(counts, 0, (size_t)N * 4, stream);
    hist_kernel<<<EB, 256, 0, stream>>>(col, counts, E);
    pscan1_kernel<<<SCB, 1024, 0, stream>>>(counts, psum, N);
    pscan2_kernel<<<1, 64, 0, stream>>>(psum, pbase);
    pscan3_kernel<<<SCB, 1024, 0, stream>>>(counts, pbase, offsets, woff, N);
    scatter_kernel<<<EB, 256, 0, stream>>>(pos, offs, row, col, woff, meta, E);
    prep_kernel<<<(NLAYERS * FF * FF + 255) / 256, 256, 0, stream>>>(
        w1, w2, u1, u2, lin_w, w1t, w2t, u1t, u2t, lin_wt);
    tab_kernel<<<NLAYERS * (TAB / 64), 256, 0, stream>>>(w1t, b1, w2t, b2, tab);
    vproj0_kernel<<<NB64, 256, 0, stream>>>(v, lin_wt, vprojA, vbuf, N);

    for (int l = 0; l < NLAYERS; l++) {
        unsigned short* vin = (l & 1) ? vprojB : vprojA;
        unsigned short* vout = (l & 1) ? vprojA : vprojB;
        layer_kernel<<<NBn, 512, 0, stream>>>(
            meta, offsets, woff, (const unsigned*)(tab + (size_t)l * TAB * FF),
            (const unsigned*)vin,
            u1t + (size_t)l * FF * FF, ub1 + (size_t)l * HH,
            u2t + (size_t)l * FF * FF, ub2 + (size_t)l * HH, vbuf,
            (l + 1 < NLAYERS) ? (lin_wt + (size_t)(l + 1) * FF * FF) : nullptr,
            vout, N);
    }
}

// Round 17
// 288.285 us; speedup vs baseline: 1.1873x; 1.1873x over previous
//
#include <hip/hip_runtime.h>
#include <hip/hip_bf16.h>
#include <math.h>

#define HH 128
#define FF 128
#define GG 50
#define NLAYERS 6
#define NPB 16
#define TAB 8192
#define TABH 9.765625e-4f    // 8.0 / 8192
#define TABINVH 1024.0f
#define SCB 32               // scan blocks
#define DP 16                // edge pipeline depth

typedef __attribute__((ext_vector_type(8))) short bf16x8;
typedef __attribute__((ext_vector_type(4))) float f32x4;

static __device__ __forceinline__ float ssp(float x) {
    return fmaxf(x, 0.f) + __logf(1.f + __expf(-fabsf(x))) - 0.6931471805599453f;
}

static __device__ __forceinline__ short f2bf(float x) {
    union { float f; unsigned u; } c; c.f = x;
    unsigned r = (c.u + 0x7FFF + ((c.u >> 16) & 1)) >> 16;
    return (short)r;
}

static __device__ __forceinline__ float bf2f_lo(unsigned p) {
    union { unsigned u; float f; } c; c.u = p << 16; return c.f;
}
static __device__ __forceinline__ float bf2f_hi(unsigned p) {
    union { unsigned u; float f; } c; c.u = p & 0xFFFF0000u; return c.f;
}

// ---------------- sort pipeline ----------------
__global__ void hist_kernel(const int* __restrict__ col, int* __restrict__ counts, int E_) {
    int e = blockIdx.x * 256 + threadIdx.x;
    if (e < E_) atomicAdd(&counts[col[e]], 1);
}

__global__ __launch_bounds__(1024) void pscan1_kernel(const int* __restrict__ counts,
                                                      int* __restrict__ psum, int N_) {
    __shared__ int wsum[16];
    const int tid = threadIdx.x;
    const int lane = tid & 63, wid = tid >> 6;
    const int chunk = (N_ + SCB - 1) / SCB;
    int i = blockIdx.x * chunk + tid;
    int val = (tid < chunk && i < N_) ? counts[i] : 0;
#pragma unroll
    for (int d = 1; d < 64; d <<= 1) val += __shfl_xor(val, d, 64);
    if (lane == 0) wsum[wid] = val;
    __syncthreads();
    if (wid == 0) {
        int s = (lane < 16) ? wsum[lane] : 0;
#pragma unroll
        for (int d = 1; d < 16; d <<= 1) s += __shfl_xor(s, d, 64);
        if (lane == 0) psum[blockIdx.x] = s;
    }
}

__global__ void pscan2_kernel(const int* __restrict__ psum, int* __restrict__ pbase) {
    const int tid = threadIdx.x;  // 64 threads
    int v = (tid < SCB) ? psum[tid] : 0;
    int x = v;
#pragma unroll
    for (int d = 1; d < 64; d <<= 1) {
        int t = __shfl_up(x, d, 64);
        if (tid >= d) x += t;
    }
    if (tid < SCB) pbase[tid] = x - v;  // exclusive
}

__global__ __launch_bounds__(1024) void pscan3_kernel(const int* __restrict__ counts,
                                                      const int* __restrict__ pbase,
                                                      int* __restrict__ offsets,
                                                      int* __restrict__ woff, int N_) {
    __shared__ int wsum[16];
    const int tid = threadIdx.x;
    const int lane = tid & 63, wid = tid >> 6;
    const int chunk = (N_ + SCB - 1) / SCB;
    int i = blockIdx.x * chunk + tid;
    int val = (tid < chunk && i < N_) ? counts[i] : 0;
    int x = val;
#pragma unroll
    for (int d = 1; d < 64; d <<= 1) {
        int t = __shfl_up(x, d, 64);
        if (lane >= d) x += t;
    }
    if (lane == 63) wsum[wid] = x;
    __syncthreads();
    if (wid == 0) {
        int s = (lane < 16) ? wsum[lane] : 0;
#pragma unroll
        for (int d = 1; d < 16; d <<= 1) {
            int t = __shfl_up(s, d, 64);
            if (lane >= d) s += t;
        }
        if (lane < 16) wsum[lane] = s;
    }
    __syncthreads();
    int woffset = (wid > 0) ? wsum[wid - 1] : 0;
    if (tid < chunk && i < N_) {
        int ex = pbase[blockIdx.x] + woffset + x - val;
        offsets[i] = ex;
        woff[i] = ex;
    }
}

// scatter: CSR slots + packed per-edge meta row(17b) | ix(13b)<<17 (nearest table idx)
__global__ void scatter_kernel(const float* __restrict__ pos,
                               const float* __restrict__ offs,
                               const int* __restrict__ row,
                               const int* __restrict__ col,
                               int* __restrict__ woff,
                               int* __restrict__ meta, int E_) {
    int e = blockIdx.x * 256 + threadIdx.x;
    if (e >= E_) return;
    int r = row[e], c = col[e];
    float dx = pos[c * 3 + 0] + offs[e * 3 + 0] - pos[r * 3 + 0];
    float dy = pos[c * 3 + 1] + offs[e * 3 + 1] - pos[r * 3 + 1];
    float dz = pos[c * 3 + 2] + offs[e * 3 + 2] - pos[r * 3 + 2];
    float d = sqrtf(dx * dx + dy * dy + dz * dz);
    int ix = (int)(d * TABINVH + 0.5f);   // nearest
    if (ix > TAB - 1) ix = TAB - 1;
    int p = atomicAdd(&woff[c], 1);
    meta[p] = r | (ix << 17);             // requires N < 131072
}

// ------------- prep: transpose + bf16 all weights -------------
__global__ __launch_bounds__(256) void prep_kernel(
    const float* __restrict__ w1, const float* __restrict__ w2,
    const float* __restrict__ u1, const float* __restrict__ u2,
    const float* __restrict__ lin_w,
    short* __restrict__ w1t, short* __restrict__ w2t,
    short* __restrict__ u1t, short* __restrict__ u2t, short* __restrict__ lin_wt) {
    int idx = blockIdx.x * 256 + threadIdx.x;
    if (idx < NLAYERS * FF * FF) {
        int l = idx >> 14, r = idx & 16383, a = r >> 7, b = r & 127;
        size_t src = (size_t)l * FF * FF + (size_t)b * FF + a;
        w2t[idx] = f2bf(w2[src]);
        u1t[idx] = f2bf(u1[src]);
        u2t[idx] = f2bf(u2[src]);
        lin_wt[idx] = f2bf(lin_w[src]);
    }
    if (idx < NLAYERS * FF * 64) {
        int l = idx >> 13, r = idx & 8191, fo = r >> 6, g = r & 63;
        w1t[idx] = f2bf(g < GG ? w1[((size_t)l * GG + g) * FF + fo] : 0.f);
    }
}

// ------- vproj0 = v(f32) @ lin_w[0] via MFMA, bf16 out; also copies v -> vbuf -------
__global__ __launch_bounds__(256) void vproj0_kernel(const float* __restrict__ vb,
                                                     const short* __restrict__ lwt,
                                                     unsigned short* __restrict__ out,
                                                     float* __restrict__ vbuf_out,
                                                     int N_) {
    const int tid = threadIdx.x;
    const int lane = tid & 63, wave = tid >> 6;
    const int l15 = lane & 15, l4 = lane >> 4;
    const int n0 = wave * 32;
    const int nb0 = blockIdx.x * 64;
    // fused residual-state init: vbuf = v
    for (int i = tid; i < 64 * 32; i += 256) {
        int r = i >> 5, c = i & 31;
        int gn = nb0 + r;
        if (gn < N_)
            *(float4*)&vbuf_out[(size_t)gn * HH + c * 4] =
                *(const float4*)&vb[(size_t)gn * HH + c * 4];
    }
    bf16x8 bw[2][4];
#pragma unroll
    for (int n = 0; n < 2; n++)
#pragma unroll
        for (int ks = 0; ks < 4; ks++)
            bw[n][ks] = *(const bf16x8*)&lwt[(n0 + n * 16 + l15) * 128 + ks * 32 + l4 * 8];
#pragma unroll
    for (int m = 0; m < 4; m++) {
        f32x4 acc0 = {0.f, 0.f, 0.f, 0.f}, acc1 = {0.f, 0.f, 0.f, 0.f};
        int arow = nb0 + m * 16 + l15;
        const float* ap = &vb[(size_t)(arow < N_ ? arow : 0) * HH];
#pragma unroll
        for (int ks = 0; ks < 4; ks++) {
            float4 x0 = *(const float4*)&ap[ks * 32 + l4 * 8];
            float4 x1 = *(const float4*)&ap[ks * 32 + l4 * 8 + 4];
            bf16x8 a = {f2bf(x0.x), f2bf(x0.y), f2bf(x0.z), f2bf(x0.w),
                        f2bf(x1.x), f2bf(x1.y), f2bf(x1.z), f2bf(x1.w)};
            acc0 = __builtin_amdgcn_mfma_f32_16x16x32_bf16(a, bw[0][ks], acc0, 0, 0, 0);
            acc1 = __builtin_amdgcn_mfma_f32_16x16x32_bf16(a, bw[1][ks], acc1, 0, 0, 0);
        }
#pragma unroll
        for (int r = 0; r < 4; r++) {
            int gn = nb0 + m * 16 + l4 * 4 + r;
            if (gn < N_) {
                out[(size_t)gn * FF + n0 + l15] = (unsigned short)f2bf(acc0[r]);
                out[(size_t)gn * FF + n0 + 16 + l15] = (unsigned short)f2bf(acc1[r]);
            }
        }
    }
}

// -------- table build: tab[l][i][f], i = nearest grid point ----
__global__ __launch_bounds__(256) void tab_kernel(
    const short* __restrict__ w1t, const float* __restrict__ b1,
    const short* __restrict__ w2t, const float* __restrict__ b2,
    unsigned short* __restrict__ tab) {
    __shared__ __align__(16) short h1_s[64 * 136];
    const int tid = threadIdx.x;
    const int lane = tid & 63, wave = tid >> 6;
    const int l15 = lane & 15, l4 = lane >> 4;
    const int n0w = wave * 32;
    const int l = blockIdx.x / (TAB / 64);
    const int tb0 = (blockIdx.x % (TAB / 64)) * 64;
    const short* w1l = w1t + (size_t)l * FF * 64;
    const short* w2l = w2t + (size_t)l * FF * FF;
    unsigned short* tabl = tab + (size_t)l * TAB * FF;

    bf16x8 bw1[2][2], bw2[2][4];
    float bias1[2], bias2[2];
#pragma unroll
    for (int n = 0; n < 2; n++) {
        const int fo = n0w + n * 16 + l15;
        bias1[n] = b1[(size_t)l * FF + fo];
        bias2[n] = b2[(size_t)l * FF + fo];
#pragma unroll
        for (int ks = 0; ks < 2; ks++)
            bw1[n][ks] = *(const bf16x8*)&w1l[fo * 64 + ks * 32 + l4 * 8];
#pragma unroll
        for (int ks = 0; ks < 4; ks++)
            bw2[n][ks] = *(const bf16x8*)&w2l[fo * 128 + ks * 32 + l4 * 8];
    }

    const float STEP = 5.0f / 49.0f;
    const float COEFF = -0.5f / (STEP * STEP);
#pragma unroll
    for (int m = 0; m < 4; m++) {
        float d = (float)(tb0 + m * 16 + l15) * TABH;
        bf16x8 a0, a1;
#pragma unroll
        for (int j = 0; j < 8; j++) {
            int g0 = l4 * 8 + j;
            float x0 = fmaf((float)g0, -STEP, d);
            a0[j] = f2bf(__expf(COEFF * x0 * x0));
            int g1 = 32 + l4 * 8 + j;
            float x1 = fmaf((float)g1, -STEP, d);
            a1[j] = (g1 < GG) ? f2bf(__expf(COEFF * x1 * x1)) : (short)0;
        }
#pragma unroll
        for (int n = 0; n < 2; n++) {
            f32x4 acc = {bias1[n], bias1[n], bias1[n], bias1[n]};
            acc = __builtin_amdgcn_mfma_f32_16x16x32_bf16(a0, bw1[n][0], acc, 0, 0, 0);
            acc = __builtin_amdgcn_mfma_f32_16x16x32_bf16(a1, bw1[n][1], acc, 0, 0, 0);
            const int f = n0w + n * 16 + l15;
#pragma unroll
            for (int r = 0; r < 4; r++)
                h1_s[(m * 16 + l4 * 4 + r) * 136 + f] = f2bf(ssp(acc[r]));
        }
    }
    __syncthreads();

#pragma unroll
    for (int m = 0; m < 4; m++) {
        f32x4 accA = {bias2[0], bias2[0], bias2[0], bias2[0]};
        f32x4 accB = {bias2[1], bias2[1], bias2[1], bias2[1]};
#pragma unroll
        for (int ks = 0; ks < 4; ks++) {
            bf16x8 a = *(const bf16x8*)&h1_s[(m * 16 + l15) * 136 + ks * 32 + l4 * 8];
            accA = __builtin_amdgcn_mfma_f32_16x16x32_bf16(a, bw2[0][ks], accA, 0, 0, 0);
            accB = __builtin_amdgcn_mfma_f32_16x16x32_bf16(a, bw2[1][ks], accB, 0, 0, 0);
        }
#pragma unroll
        for (int r = 0; r < 4; r++) {
            int entry = tb0 + m * 16 + l4 * 4 + r;
            float de = (float)entry * TABH;
            float C = 0.5f * (cosf(de * 0.6283185307179586f) + 1.0f);
            tabl[(size_t)entry * FF + n0w + l15] = (unsigned short)f2bf(accA[r] * C);
            tabl[(size_t)entry * FF + n0w + 16 + l15] = (unsigned short)f2bf(accB[r] * C);
        }
    }
}

// ===== fused layer: 8-wave/512-thr, NPB=16; R15 walk (2 independent per-node
// DP=16 pipelines, 2 accumulators, VGPR ~32) =====
__global__ __launch_bounds__(512) void layer_kernel(
    const int* __restrict__ meta,
    const int* __restrict__ off_start, const int* __restrict__ off_end,
    const unsigned* __restrict__ tab, const unsigned* __restrict__ vin,
    const short* __restrict__ u1t, const float* __restrict__ ub1,
    const short* __restrict__ u2t, const float* __restrict__ ub2,
    float* __restrict__ vb, const short* __restrict__ lwt_next,
    unsigned short* __restrict__ vout, int N_) {
    __shared__ __align__(16) float agg_s[NPB * 132];
    __shared__ __align__(16) short t1_s[NPB * 136];
    short* t2_s = (short*)agg_s;

    const int tid = threadIdx.x;
    const int lane = tid & 63, wave = tid >> 6;   // 8 waves
    const int l15 = lane & 15, l4 = lane >> 4;
    const int n0c = wave * 16;
    const int nb0 = blockIdx.x * NPB;

    // ---- edge aggregation: wave owns 2 nodes; DP-deep batched pipeline
#pragma unroll
    for (int s = 0; s < 2; s++) {
        const int nl = wave * 2 + s;
        const int n = nb0 + nl;
        float acc0 = 0.f, acc1 = 0.f;
        if (n < N_) {
            const int e0 = __builtin_amdgcn_readfirstlane(off_start[n]);
            const int e1 = __builtin_amdgcn_readfirstlane(off_end[n]);
            if (e1 > e0) {
                int mmn[DP];
#pragma unroll
                for (int j = 0; j < DP; j++) {
                    int e = e0 + j; if (e >= e1) e = e1 - 1;
                    mmn[j] = meta[e];
                }
                for (int base = e0; base < e1; base += DP) {
                    int mw[DP];
#pragma unroll
                    for (int j = 0; j < DP; j++)
                        mw[j] = __builtin_amdgcn_readfirstlane(mmn[j]);
                    unsigned tp[DP], vp[DP];
#pragma unroll
                    for (int j = 0; j < DP; j++) {
                        const int r_ = mw[j] & 0x1ffff;
                        const int ix = (int)((unsigned)mw[j] >> 17);
                        tp[j] = tab[(size_t)ix * 64 + lane];
                        vp[j] = vin[(size_t)r_ * 64 + lane];
                    }
                    const int nb2 = base + DP;
                    if (nb2 < e1) {
#pragma unroll
                        for (int j = 0; j < DP; j++) {
                            int e = nb2 + j; if (e >= e1) e = e1 - 1;
                            mmn[j] = meta[e];
                        }
                    }
#pragma unroll
                    for (int j = 0; j < DP; j++) {
                        if (base + j < e1) {   // scalar-uniform branch
                            acc0 = fmaf(bf2f_lo(tp[j]), bf2f_lo(vp[j]), acc0);
                            acc1 = fmaf(bf2f_hi(tp[j]), bf2f_hi(vp[j]), acc1);
                        }
                    }
                }
            }
        }
        agg_s[nl * 132 + 2 * lane] = acc0;
        agg_s[nl * 132 + 2 * lane + 1] = acc1;
    }
    __syncthreads();

    // ---- MLP GEMM1: t1 = ssp(agg @ u1 + ub1); wave does 16x16 tile
    {
        bf16x8 bw[4];
        const float bias = ub1[n0c + l15];
#pragma unroll
        for (int ks = 0; ks < 4; ks++)
            bw[ks] = *(const bf16x8*)&u1t[(n0c + l15) * 128 + ks * 32 + l4 * 8];
        const float* ap = &agg_s[l15 * 132];
        f32x4 acc = {bias, bias, bias, bias};
#pragma unroll
        for (int ks = 0; ks < 4; ks++) {
            float4 x0 = *(const float4*)&ap[ks * 32 + l4 * 8];
            float4 x1 = *(const float4*)&ap[ks * 32 + l4 * 8 + 4];
            bf16x8 a = {f2bf(x0.x), f2bf(x0.y), f2bf(x0.z), f2bf(x0.w),
                        f2bf(x1.x), f2bf(x1.y), f2bf(x1.z), f2bf(x1.w)};
            acc = __builtin_amdgcn_mfma_f32_16x16x32_bf16(a, bw[ks], acc, 0, 0, 0);
        }
#pragma unroll
        for (int r = 0; r < 4; r++) {
            int er = l4 * 4 + r;
            t1_s[er * 136 + n0c + l15] = f2bf(ssp(acc[r]));
        }
    }
    __syncthreads();

    // ---- MLP GEMM2: v_new = v + (t1 @ u2 + ub2); write vb + t2_s (aliases agg)
    {
        bf16x8 bw[4];
        const float bias = ub2[n0c + l15];
#pragma unroll
        for (int ks = 0; ks < 4; ks++)
            bw[ks] = *(const bf16x8*)&u2t[(n0c + l15) * 128 + ks * 32 + l4 * 8];
        f32x4 acc = {bias, bias, bias, bias};
#pragma unroll
        for (int ks = 0; ks < 4; ks++) {
            bf16x8 a = *(const bf16x8*)&t1_s[(l15) * 136 + ks * 32 + l4 * 8];
            acc = __builtin_amdgcn_mfma_f32_16x16x32_bf16(a, bw[ks], acc, 0, 0, 0);
        }
        __syncthreads();   // agg reads done before t2 overwrite
#pragma unroll
        for (int r = 0; r < 4; r++) {
            int er = l4 * 4 + r;
            int gn = nb0 + er;
            if (gn < N_) {
                size_t i0 = (size_t)gn * HH + n0c + l15;
                float v0 = vb[i0] + acc[r];
                vb[i0] = v0;
                t2_s[er * 136 + n0c + l15] = f2bf(v0);
            } else {
                t2_s[er * 136 + n0c + l15] = 0;
            }
        }
    }
    __syncthreads();

    // ---- MLP GEMM3: vout = v_new @ lin_w[l+1] (bf16)
    if (lwt_next) {
        bf16x8 bw[4];
#pragma unroll
        for (int ks = 0; ks < 4; ks++)
            bw[ks] = *(const bf16x8*)&lwt_next[(n0c + l15) * 128 + ks * 32 + l4 * 8];
        f32x4 acc = {0.f, 0.f, 0.f, 0.f};
#pragma unroll
        for (int ks = 0; ks < 4; ks++) {
            bf16x8 a = *(const bf16x8*)&t2_s[(l15) * 136 + ks * 32 + l4 * 8];
            acc = __builtin_amdgcn_mfma_f32_16x16x32_bf16(a, bw[ks], acc, 0, 0, 0);
        }
#pragma unroll
        for (int r = 0; r < 4; r++) {
            int gn = nb0 + l4 * 4 + r;
            if (gn < N_) {
                vout[(size_t)gn * FF + n0c + l15] = (unsigned short)f2bf(acc[r]);
            }
        }
    }
}

extern "C" void kernel_launch(void* const* d_in, const int* in_sizes, int n_in,
                              void* d_out, int out_size, void* d_ws, size_t ws_size,
                              hipStream_t stream) {
    const float* v = (const float*)d_in[0];
    const float* pos = (const float*)d_in[1];
    const float* offs = (const float*)d_in[2];
    const int* edges = (const int*)d_in[3];
    const float* lin_w = (const float*)d_in[4];
    const float* w1 = (const float*)d_in[5];
    const float* b1 = (const float*)d_in[6];
    const float* w2 = (const float*)d_in[7];
    const float* b2 = (const float*)d_in[8];
    const float* u1 = (const float*)d_in[9];
    const float* ub1 = (const float*)d_in[10];
    const float* u2 = (const float*)d_in[11];
    const float* ub2 = (const float*)d_in[12];

    const int N = in_sizes[0] / HH;
    const int E = in_sizes[3] / 2;
    const int* row = edges;
    const int* col = edges + E;

    char* base = (char*)d_ws;
    int* counts = (int*)base;    base += (size_t)N * 4;
    int* woff = (int*)base;      base += (size_t)N * 4;
    int* offsets = (int*)base;   base += (size_t)N * 4;
    int* psum = (int*)base;      base += (size_t)SCB * 4;
    int* pbase = (int*)base;     base += (size_t)SCB * 4 + 24;  // keep align
    int* meta = (int*)base;      base += (size_t)E * 4;
    unsigned short* vprojA = (unsigned short*)base; base += (size_t)N * FF * 2;
    unsigned short* vprojB = (unsigned short*)base; base += (size_t)N * FF * 2;
    short* w1t = (short*)base;   base += (size_t)NLAYERS * FF * 64 * 2;
    short* w2t = (short*)base;   base += (size_t)NLAYERS * FF * FF * 2;
    short* u1t = (short*)base;   base += (size_t)NLAYERS * FF * FF * 2;
    short* u2t = (short*)base;   base += (size_t)NLAYERS * FF * FF * 2;
    short* lin_wt = (short*)base; base += (size_t)NLAYERS * FF * FF * 2;
    unsigned short* tab = (unsigned short*)base;  // 6 * 8192 * 128 bf16 = 12.6 MB

    float* vbuf = (float*)d_out;   // residual state lives in d_out

    const int EB = (E + 255) / 256;
    const int NB64 = (N + 63) / 64;
    const int NBn = (N + NPB - 1) / NPB;

    hipMemsetAsync(counts, 0, (size_t)N * 4, stream);
    hist_kernel<<<EB, 256, 0, stream>>>(col, counts, E);
    pscan1_kernel<<<SCB, 1024, 0, stream>>>(counts, psum, N);
    pscan2_kernel<<<1, 64, 0, stream>>>(psum, pbase);
    pscan3_kernel<<<SCB, 1024, 0, stream>>>(counts, pbase, offsets, woff, N);
    scatter_kernel<<<EB, 256, 0, stream>>>(pos, offs, row, col, woff, meta, E);
    prep_kernel<<<(NLAYERS * FF * FF + 255) / 256, 256, 0, stream>>>(
        w1, w2, u1, u2, lin_w, w1t, w2t, u1t, u2t, lin_wt);
    tab_kernel<<<NLAYERS * (TAB / 64), 256, 0, stream>>>(w1t, b1, w2t, b2, tab);
    vproj0_kernel<<<NB64, 256, 0, stream>>>(v, lin_wt, vprojA, vbuf, N);

    for (int l = 0; l < NLAYERS; l++) {
        unsigned short* vin = (l & 1) ? vprojB : vprojA;
        unsigned short* vout = (l & 1) ? vprojA : vprojB;
        layer_kernel<<<NBn, 512, 0, stream>>>(
            meta, offsets, woff, (const unsigned*)(tab + (size_t)l * TAB * FF),
            (const unsigned*)vin,
            u1t + (size_t)l * FF * FF, ub1 + (size_t)l * HH,
            u2t + (size_t)l * FF * FF, ub2 + (size_t)l * HH, vbuf,
            (l + 1 < NLAYERS) ? (lin_wt + (size_t)(l + 1) * FF * FF) : nullptr,
            vout, N);
    }
}